// Round 3
// baseline (3758.549 us; speedup 1.0000x reference)
//
#include <hip/hip_runtime.h>
#include <hip/hip_bf16.h>
#include <stdint.h>

#define ALPHA_F 0.2f
#define K_STEPS 10

typedef __attribute__((ext_vector_type(8))) short short8;
typedef __attribute__((ext_vector_type(4))) float f32x4;
typedef __attribute__((ext_vector_type(4))) unsigned short u16x4;

__device__ __forceinline__ float bf2f(unsigned short u) {
  union { unsigned int i; float f; } v; v.i = ((unsigned int)u) << 16; return v.f;
}
__device__ __forceinline__ unsigned short f2bf(float f) {
  unsigned int x = __float_as_uint(f);
  unsigned int r = (x + 0x7fffu + ((x >> 16) & 1u)) >> 16;
  return (unsigned short)r;
}

__device__ __forceinline__ void glds16(const void* g, void* l) {
  __builtin_amdgcn_global_load_lds(
      (const __attribute__((address_space(1))) void*)g,
      (__attribute__((address_space(3))) void*)l, 16, 0, 0);
}

// ---------------- graph build ----------------

__global__ void k_init_deg(int* __restrict__ deg, int n) {
  int i = blockIdx.x * blockDim.x + threadIdx.x;
  if (i < n) deg[i] = 1;  // self-loop
}

__global__ void k_hist(const int* __restrict__ dst, int* __restrict__ deg, int E) {
  int e = blockIdx.x * blockDim.x + threadIdx.x;
  if (e < E) atomicAdd(&deg[dst[e]], 1);
}

// single-block exclusive scan over n counts -> rowptr[0..n]
__global__ void k_scan(const int* __restrict__ counts, int* __restrict__ rowptr, int n) {
  __shared__ int tmp[1024];
  __shared__ int carry_s;
  const int tid = threadIdx.x;
  if (tid == 0) carry_s = 0;
  __syncthreads();
  for (int base = 0; base < n; base += 1024) {
    int idx = base + tid;
    int v = (idx < n) ? counts[idx] : 0;
    tmp[tid] = v;
    __syncthreads();
    #pragma unroll
    for (int off = 1; off < 1024; off <<= 1) {
      int t = (tid >= off) ? tmp[tid - off] : 0;
      __syncthreads();
      tmp[tid] += t;
      __syncthreads();
    }
    int c = carry_s;
    if (idx < n) rowptr[idx] = c + tmp[tid] - v;  // exclusive
    __syncthreads();
    if (tid == 0) carry_s = c + tmp[1023];
    __syncthreads();
  }
  if (tid == 0) rowptr[n] = carry_s;
}

__global__ void k_dinv_cursor(const int* __restrict__ deg, const int* __restrict__ rowptr,
                              float* __restrict__ dinv, int* __restrict__ cursor, int n) {
  int i = blockIdx.x * blockDim.x + threadIdx.x;
  if (i < n) {
    dinv[i] = 1.0f / sqrtf((float)deg[i]);  // deg >= 1 always (self-loop)
    cursor[i] = rowptr[i];
  }
}

__global__ void k_scatter(const int* __restrict__ src, const int* __restrict__ dst,
                          int* __restrict__ cursor, int* __restrict__ col,
                          float* __restrict__ wgt, const float* __restrict__ dinv,
                          int E, int n) {
  int idx = blockIdx.x * blockDim.x + threadIdx.x;
  if (idx >= E + n) return;
  int s, d;
  if (idx < E) { s = src[idx]; d = dst[idx]; }
  else         { s = d = idx - E; }
  int pos = atomicAdd(&cursor[d], 1);
  col[pos] = s;
  wgt[pos] = dinv[s];
}

// ---------------- converts ----------------

// fp32 -> bf16, 8 elems/thread, zero-fill pad rows
__global__ void k_f2b8(const float* __restrict__ src, unsigned short* __restrict__ dst,
                       int validRows, int cols, long total8) {
  long idx = (long)blockIdx.x * blockDim.x + threadIdx.x;
  if (idx >= total8) return;
  size_t base = (size_t)idx * 8;
  int row = (int)(base / (size_t)cols);
  uint4 o;
  if (row < validRows) {
    const float4 f0 = *reinterpret_cast<const float4*>(src + base);
    const float4 f1 = *reinterpret_cast<const float4*>(src + base + 4);
    o.x = f2bf(f0.x) | ((unsigned)f2bf(f0.y) << 16);
    o.y = f2bf(f0.z) | ((unsigned)f2bf(f0.w) << 16);
    o.z = f2bf(f1.x) | ((unsigned)f2bf(f1.y) << 16);
    o.w = f2bf(f1.z) | ((unsigned)f2bf(f1.w) << 16);
  } else {
    o = make_uint4(0, 0, 0, 0);
  }
  *reinterpret_cast<uint4*>(dst + base) = o;
}

// W [K][Nw] fp32 -> Wt [Nw][K] bf16
__global__ void k_wtrans(const float* __restrict__ W, unsigned short* __restrict__ Wt,
                         int K, int Nw) {
  int idx = blockIdx.x * blockDim.x + threadIdx.x;
  if (idx >= K * Nw) return;
  int nn = idx / K, kk = idx - nn * K;
  Wt[(size_t)nn * K + kk] = f2bf(W[(size_t)kk * Nw + nn]);
}

// h0 row-major fp32 [N][256] -> h0c chunk-major fp32 [8][N][32] + state bf16 [8][N][32]
// thread handles 8 dims: idx = (c*n + i)*4 + q
__global__ void k_repack(const float* __restrict__ h0, float* __restrict__ h0c,
                         unsigned short* __restrict__ st, int n) {
  long idx = (long)blockIdx.x * blockDim.x + threadIdx.x;
  if (idx >= (long)n * 32) return;  // 8*n*4
  const int q = (int)(idx & 3);
  const long ci = idx >> 2;
  const int i = (int)(ci % n);
  const int c = (int)(ci / n);
  const float* sp = h0 + (size_t)i * 256 + c * 32 + q * 8;
  const float4 f0 = *reinterpret_cast<const float4*>(sp);
  const float4 f1 = *reinterpret_cast<const float4*>(sp + 4);
  float* dp = h0c + ci * 32 + q * 8;
  *reinterpret_cast<float4*>(dp) = f0;
  *reinterpret_cast<float4*>(dp + 4) = f1;
  uint4 o;
  o.x = f2bf(f0.x) | ((unsigned)f2bf(f0.y) << 16);
  o.y = f2bf(f0.z) | ((unsigned)f2bf(f0.w) << 16);
  o.z = f2bf(f1.x) | ((unsigned)f2bf(f1.y) << 16);
  o.w = f2bf(f1.z) | ((unsigned)f2bf(f1.w) << 16);
  *reinterpret_cast<uint4*>(st + ci * 32 + q * 8) = o;
}

// ---------------- MFMA GEMM ----------------
// C[M][Nn] = A[M][K]_bf16 @ Bt[Nn][K]_bf16^T + bias, 128x128 tile, BK=32,
// 256 threads = 4 waves (2x2), each wave 64x64 = 4x4 fragments of 16x16x32.

template<bool OUT_BF16, bool RELU>
__global__ __launch_bounds__(256)
void k_gemm_mfma(const unsigned short* __restrict__ A,
                 const unsigned short* __restrict__ Bt,
                 const float* __restrict__ bias,
                 void* __restrict__ C, int Nn, int K) {
  __shared__ unsigned short As[128 * 32];
  __shared__ unsigned short Bs[128 * 32];
  const int tid = threadIdx.x;
  const int lane = tid & 63;
  const int wid = tid >> 6;
  const int wr = wid >> 1, wc = wid & 1;
  const int bm = blockIdx.y * 128;
  const int bn = blockIdx.x * 128;

  f32x4 acc[4][4];
  #pragma unroll
  for (int i = 0; i < 4; ++i)
    #pragma unroll
    for (int j = 0; j < 4; ++j) acc[i][j] = (f32x4)0.f;

  const int srow = tid >> 2;
  const int skg = (tid & 3) << 3;
  const unsigned short* Ag = A + (size_t)(bm + srow) * K + skg;
  const unsigned short* Bg = Bt + (size_t)(bn + srow) * K + skg;
  unsigned short* lA = As + (wid << 9);
  unsigned short* lB = Bs + (wid << 9);

  const int frow = lane & 15;
  const int fk = (lane >> 4) << 3;

  for (int k0 = 0; k0 < K; k0 += 32) {
    __syncthreads();
    glds16(Ag + k0, lA);
    glds16(Ag + (size_t)64 * K + k0, lA + 2048);
    glds16(Bg + k0, lB);
    glds16(Bg + (size_t)64 * K + k0, lB + 2048);
    __syncthreads();

    short8 af[4], bq[4];
    #pragma unroll
    for (int mi = 0; mi < 4; ++mi)
      af[mi] = *reinterpret_cast<const short8*>(&As[(wr * 64 + mi * 16 + frow) * 32 + fk]);
    #pragma unroll
    for (int ni = 0; ni < 4; ++ni)
      bq[ni] = *reinterpret_cast<const short8*>(&Bs[(wc * 64 + ni * 16 + frow) * 32 + fk]);
    #pragma unroll
    for (int mi = 0; mi < 4; ++mi)
      #pragma unroll
      for (int ni = 0; ni < 4; ++ni)
        acc[mi][ni] = __builtin_amdgcn_mfma_f32_16x16x32_bf16(af[mi], bq[ni], acc[mi][ni], 0, 0, 0);
  }

  const int r0 = bm + wr * 64;
  const int c0 = bn + wc * 64;
  #pragma unroll
  for (int ni = 0; ni < 4; ++ni) {
    const int c = c0 + ni * 16 + (lane & 15);
    const float bv = bias[c];
    #pragma unroll
    for (int mi = 0; mi < 4; ++mi) {
      #pragma unroll
      for (int r = 0; r < 4; ++r) {
        const int row = r0 + mi * 16 + ((lane >> 4) << 2) + r;
        float v = acc[mi][ni][r] + bv;
        if constexpr (RELU) v = fmaxf(v, 0.f);
        if constexpr (OUT_BF16)
          ((unsigned short*)C)[(size_t)row * Nn + c] = f2bf(v);
        else
          ((float*)C)[(size_t)row * Nn + c] = v;
      }
    }
  }
}

// ---------------- APPNP propagation step (XCD dim-chunk affinity) ----------------
// state bf16 chunk-major [8][N][32]. chunk = blockIdx.x & 7 -> XCD via round-robin.
// Wave: lane = (edge subgroup g 0..7) x (dim quad d 0..7). 8 edges in flight,
// each gather = 8 lanes x 8B = one 64B segment. fp32 accumulate, shfl_xor reduce.

template<bool FINAL>
__global__ __launch_bounds__(256)
void k_appnp_chunk(const unsigned short* __restrict__ hb,
                   const float* __restrict__ h0c,
                   void* __restrict__ outp,
                   const int* __restrict__ rowptr,
                   const int* __restrict__ col,
                   const float* __restrict__ wgt,
                   const float* __restrict__ dinv, int n) {
  const int c = blockIdx.x & 7;
  const int grp = blockIdx.x >> 3;
  const int wave = threadIdx.x >> 6;
  const int lane = threadIdx.x & 63;
  const int g = lane >> 3;
  const int d = lane & 7;
  const unsigned short* hc = hb + (size_t)c * n * 32;
  const int i0 = grp * 32 + wave * 8;
  for (int t = 0; t < 8; ++t) {
    const int i = i0 + t;
    if (i >= n) return;
    const int beg = rowptr[i];
    const int end = rowptr[i + 1];
    float a0 = 0.f, a1 = 0.f, a2 = 0.f, a3 = 0.f;
    for (int e = beg + g; e < end; e += 8) {
      const int j = __builtin_nontemporal_load(col + e);
      const float w = __builtin_nontemporal_load(wgt + e);
      const u16x4 hv = *reinterpret_cast<const u16x4*>(hc + (size_t)j * 32 + d * 4);
      a0 += w * bf2f(hv.x); a1 += w * bf2f(hv.y);
      a2 += w * bf2f(hv.z); a3 += w * bf2f(hv.w);
    }
    #pragma unroll
    for (int m = 8; m < 64; m <<= 1) {
      a0 += __shfl_xor(a0, m);
      a1 += __shfl_xor(a1, m);
      a2 += __shfl_xor(a2, m);
      a3 += __shfl_xor(a3, m);
    }
    if (lane < 8) {
      const float s = (1.0f - ALPHA_F) * dinv[i];
      const f32x4 h0v = __builtin_nontemporal_load(
          reinterpret_cast<const f32x4*>(h0c + ((size_t)c * n + i) * 32 + d * 4));
      const float o0 = s * a0 + ALPHA_F * h0v.x;
      const float o1 = s * a1 + ALPHA_F * h0v.y;
      const float o2 = s * a2 + ALPHA_F * h0v.z;
      const float o3 = s * a3 + ALPHA_F * h0v.w;
      if constexpr (FINAL) {
        f32x4 o; o.x = o0; o.y = o1; o.z = o2; o.w = o3;
        __builtin_nontemporal_store(o, reinterpret_cast<f32x4*>(
            (float*)outp + (size_t)i * 256 + c * 32 + d * 4));
      } else {
        u16x4 o;
        o.x = f2bf(o0); o.y = f2bf(o1); o.z = f2bf(o2); o.w = f2bf(o3);
        *reinterpret_cast<u16x4*>((unsigned short*)outp + ((size_t)c * n + i) * 32 + d * 4) = o;
      }
    }
  }
}

// ---------------- launch ----------------

extern "C" void kernel_launch(void* const* d_in, const int* in_sizes, int n_in,
                              void* d_out, int out_size, void* d_ws, size_t ws_size,
                              hipStream_t stream) {
  const float* x  = (const float*)d_in[0];
  const int*   ei = (const int*)d_in[1];
  const float* W1 = (const float*)d_in[2];
  const float* b1 = (const float*)d_in[3];
  const float* W2 = (const float*)d_in[4];
  const float* b2 = (const float*)d_in[5];
  const float* W3 = (const float*)d_in[6];
  const float* b3 = (const float*)d_in[7];

  const int HID  = in_sizes[3];            // 512
  const int IN   = in_sizes[2] / HID;      // 512
  const int OUTD = in_sizes[7];            // 256
  const int E    = in_sizes[1] / 2;        // 1,600,000
  const int N    = in_sizes[0] / IN;       // 50,000
  const int Mpad = (N + 127) & ~127;       // 50,048
  const int* src = ei;
  const int* dst = ei + E;

  char* ws = (char*)d_ws;
  size_t off = 0;
  auto alloc = [&](size_t bytes) {
    char* p = ws + off;
    off += (bytes + 255) & ~(size_t)255;
    return p;
  };
  // R1: xb [Mpad][IN] bf16 -> h2 [Mpad][HID] bf16 -> h0c fp32 [8][N][32]
  char* R1 = alloc((size_t)Mpad * ((IN > HID) ? IN : HID) * 2);
  // R2: h1 [Mpad][HID] bf16 -> stateA bf16 [8][N][32]
  char* R2 = alloc((size_t)Mpad * HID * 2);
  // R4: h0 row-major fp32 [Mpad][OUTD] -> stateB bf16 [8][N][32]
  char* R4 = alloc((size_t)Mpad * OUTD * 4);
  int*   deg    = (int*)alloc((size_t)N * 4);
  int*   rowptr = (int*)alloc((size_t)(N + 1) * 4);
  int*   cursor = (int*)alloc((size_t)N * 4);
  float* dinv   = (float*)alloc((size_t)N * 4);
  int*   col    = (int*)alloc((size_t)(E + N) * 4);
  float* wgt    = (float*)alloc((size_t)(E + N) * 4);
  unsigned short* W1t = (unsigned short*)alloc((size_t)IN * HID * 2);
  unsigned short* W2t = (unsigned short*)alloc((size_t)HID * HID * 2);
  unsigned short* W3t = (unsigned short*)alloc((size_t)HID * OUTD * 2);
  (void)ws_size; (void)n_in; (void)out_size;

  unsigned short* xb = (unsigned short*)R1;
  unsigned short* h1 = (unsigned short*)R2;
  unsigned short* h2 = (unsigned short*)R1;
  float* h0 = (float*)R4;                       // row-major GEMM3 out
  float* h0c = (float*)R1;                      // chunk-major (after h2 consumed)
  unsigned short* stateA = (unsigned short*)R2; // chunk-major bf16
  unsigned short* stateB = (unsigned short*)R4; // overwrites h0 after repack

  // graph build
  k_init_deg<<<(N + 255) / 256, 256, 0, stream>>>(deg, N);
  k_hist<<<(E + 255) / 256, 256, 0, stream>>>(dst, deg, E);
  k_scan<<<1, 1024, 0, stream>>>(deg, rowptr, N);
  k_dinv_cursor<<<(N + 255) / 256, 256, 0, stream>>>(deg, rowptr, dinv, cursor, N);
  k_scatter<<<(E + N + 255) / 256, 256, 0, stream>>>(src, dst, cursor, col, wgt, dinv, E, N);

  // converts
  {
    long total8 = (long)Mpad * IN / 8;
    k_f2b8<<<(int)((total8 + 255) / 256), 256, 0, stream>>>(x, xb, N, IN, total8);
    k_wtrans<<<(IN * HID + 255) / 256, 256, 0, stream>>>(W1, W1t, IN, HID);
    k_wtrans<<<(HID * HID + 255) / 256, 256, 0, stream>>>(W2, W2t, HID, HID);
    k_wtrans<<<(HID * OUTD + 255) / 256, 256, 0, stream>>>(W3, W3t, HID, OUTD);
  }

  // MLP encoder (MFMA)
  {
    dim3 blk(256);
    dim3 g1(HID / 128, Mpad / 128);
    k_gemm_mfma<true, true><<<g1, blk, 0, stream>>>(xb, W1t, b1, h1, HID, IN);
    k_gemm_mfma<true, true><<<g1, blk, 0, stream>>>(h1, W2t, b2, h2, HID, HID);
    dim3 g3(OUTD / 128, Mpad / 128);
    k_gemm_mfma<false, false><<<g3, blk, 0, stream>>>(h2, W3t, b3, h0, OUTD, HID);
  }

  // repack: h0 row-major -> h0c chunk-major fp32 + stateA chunk-major bf16
  {
    long total = (long)N * 32;  // 8*N*4 threads
    k_repack<<<(int)((total + 255) / 256), 256, 0, stream>>>(h0, h0c, stateA, N);
  }

  // APPNP propagation: chunked; steps 0..8 ping-pong states, step 9 writes d_out
  {
    const int ngrp = (N + 31) / 32;
    const int nblk = ngrp * 8;
    const unsigned short* cur = stateA;
    for (int step = 0; step < K_STEPS - 1; ++step) {
      unsigned short* dbuf = (step % 2 == 0) ? stateB : stateA;
      k_appnp_chunk<false><<<nblk, 256, 0, stream>>>(cur, h0c, dbuf, rowptr, col, wgt, dinv, N);
      cur = dbuf;
    }
    k_appnp_chunk<true><<<nblk, 256, 0, stream>>>(cur, h0c, d_out, rowptr, col, wgt, dinv, N);
  }
}

// Round 5
// 1661.961 us; speedup vs baseline: 2.2615x; 2.2615x over previous
//
#include <hip/hip_runtime.h>
#include <hip/hip_bf16.h>
#include <stdint.h>

#define ALPHA_F 0.2f
#define K_STEPS 10

typedef __attribute__((ext_vector_type(8))) short short8;
typedef __attribute__((ext_vector_type(4))) float f32x4;
typedef __attribute__((ext_vector_type(4))) unsigned short u16x4;
typedef __attribute__((ext_vector_type(2))) int i32x2;

__device__ __forceinline__ float bf2f(unsigned short u) {
  union { unsigned int i; float f; } v; v.i = ((unsigned int)u) << 16; return v.f;
}
__device__ __forceinline__ unsigned short f2bf(float f) {
  unsigned int x = __float_as_uint(f);
  unsigned int r = (x + 0x7fffu + ((x >> 16) & 1u)) >> 16;
  return (unsigned short)r;
}

__device__ __forceinline__ void glds16(const void* g, void* l) {
  __builtin_amdgcn_global_load_lds(
      (const __attribute__((address_space(1))) void*)g,
      (__attribute__((address_space(3))) void*)l, 16, 0, 0);
}

// ---------------- graph build ----------------

__global__ void k_init_deg(int* __restrict__ deg, int n) {
  int i = blockIdx.x * blockDim.x + threadIdx.x;
  if (i < n) deg[i] = 1;  // self-loop
}

__global__ void k_hist(const int* __restrict__ dst, int* __restrict__ deg, int E) {
  int e = blockIdx.x * blockDim.x + threadIdx.x;
  if (e < E) atomicAdd(&deg[dst[e]], 1);
}

// single-block exclusive scan over n counts -> rowptr[0..n]
__global__ void k_scan(const int* __restrict__ counts, int* __restrict__ rowptr, int n) {
  __shared__ int tmp[1024];
  __shared__ int carry_s;
  const int tid = threadIdx.x;
  if (tid == 0) carry_s = 0;
  __syncthreads();
  for (int base = 0; base < n; base += 1024) {
    int idx = base + tid;
    int v = (idx < n) ? counts[idx] : 0;
    tmp[tid] = v;
    __syncthreads();
    #pragma unroll
    for (int off = 1; off < 1024; off <<= 1) {
      int t = (tid >= off) ? tmp[tid - off] : 0;
      __syncthreads();
      tmp[tid] += t;
      __syncthreads();
    }
    int c = carry_s;
    if (idx < n) rowptr[idx] = c + tmp[tid] - v;  // exclusive
    __syncthreads();
    if (tid == 0) carry_s = c + tmp[1023];
    __syncthreads();
  }
  if (tid == 0) rowptr[n] = carry_s;
}

__global__ void k_dinv_cursor(const int* __restrict__ deg, const int* __restrict__ rowptr,
                              float* __restrict__ dinv, int* __restrict__ cursor, int n) {
  int i = blockIdx.x * blockDim.x + threadIdx.x;
  if (i < n) {
    dinv[i] = 1.0f / sqrtf((float)deg[i]);  // deg >= 1 always (self-loop)
    cursor[i] = rowptr[i];
  }
}

// edge[pos] = {src, bits(dinv[src])}
__global__ void k_scatter(const int* __restrict__ src, const int* __restrict__ dst,
                          int* __restrict__ cursor, i32x2* __restrict__ edge,
                          const float* __restrict__ dinv, int E, int n) {
  int idx = blockIdx.x * blockDim.x + threadIdx.x;
  if (idx >= E + n) return;
  int s, d;
  if (idx < E) { s = src[idx]; d = dst[idx]; }
  else         { s = d = idx - E; }
  int pos = atomicAdd(&cursor[d], 1);
  i32x2 e;
  e.x = s;
  e.y = __float_as_int(dinv[s]);
  edge[pos] = e;
}

// ---------------- converts ----------------

// fp32 -> bf16, 8 elems/thread, zero-fill pad rows
__global__ void k_f2b8(const float* __restrict__ src, unsigned short* __restrict__ dst,
                       int validRows, int cols, long total8) {
  long idx = (long)blockIdx.x * blockDim.x + threadIdx.x;
  if (idx >= total8) return;
  size_t base = (size_t)idx * 8;
  int row = (int)(base / (size_t)cols);
  uint4 o;
  if (row < validRows) {
    const float4 f0 = *reinterpret_cast<const float4*>(src + base);
    const float4 f1 = *reinterpret_cast<const float4*>(src + base + 4);
    o.x = f2bf(f0.x) | ((unsigned)f2bf(f0.y) << 16);
    o.y = f2bf(f0.z) | ((unsigned)f2bf(f0.w) << 16);
    o.z = f2bf(f1.x) | ((unsigned)f2bf(f1.y) << 16);
    o.w = f2bf(f1.z) | ((unsigned)f2bf(f1.w) << 16);
  } else {
    o = make_uint4(0, 0, 0, 0);
  }
  *reinterpret_cast<uint4*>(dst + base) = o;
}

// W [K][Nw] fp32 -> Wt [Nw][K] bf16
__global__ void k_wtrans(const float* __restrict__ W, unsigned short* __restrict__ Wt,
                         int K, int Nw) {
  int idx = blockIdx.x * blockDim.x + threadIdx.x;
  if (idx >= K * Nw) return;
  int nn = idx / K, kk = idx - nn * K;
  Wt[(size_t)nn * K + kk] = f2bf(W[(size_t)kk * Nw + nn]);
}

// ---------------- MFMA GEMM ----------------
// C[M][Nn] = A[M][K]_bf16 @ Bt[Nn][K]_bf16^T + bias, 128x128 tile, BK=32,
// 256 threads = 4 waves (2x2), each wave 64x64 = 4x4 fragments of 16x16x32.

template<bool OUT_BF16, bool RELU>
__global__ __launch_bounds__(256)
void k_gemm_mfma(const unsigned short* __restrict__ A,
                 const unsigned short* __restrict__ Bt,
                 const float* __restrict__ bias,
                 void* __restrict__ C, int Nn, int K) {
  __shared__ unsigned short As[128 * 32];
  __shared__ unsigned short Bs[128 * 32];
  const int tid = threadIdx.x;
  const int lane = tid & 63;
  const int wid = tid >> 6;
  const int wr = wid >> 1, wc = wid & 1;
  const int bm = blockIdx.y * 128;
  const int bn = blockIdx.x * 128;

  f32x4 acc[4][4];
  #pragma unroll
  for (int i = 0; i < 4; ++i)
    #pragma unroll
    for (int j = 0; j < 4; ++j) acc[i][j] = (f32x4)0.f;

  const int srow = tid >> 2;
  const int skg = (tid & 3) << 3;
  const unsigned short* Ag = A + (size_t)(bm + srow) * K + skg;
  const unsigned short* Bg = Bt + (size_t)(bn + srow) * K + skg;
  unsigned short* lA = As + (wid << 9);
  unsigned short* lB = Bs + (wid << 9);

  const int frow = lane & 15;
  const int fk = (lane >> 4) << 3;

  for (int k0 = 0; k0 < K; k0 += 32) {
    __syncthreads();
    glds16(Ag + k0, lA);
    glds16(Ag + (size_t)64 * K + k0, lA + 2048);
    glds16(Bg + k0, lB);
    glds16(Bg + (size_t)64 * K + k0, lB + 2048);
    __syncthreads();

    short8 af[4], bq[4];
    #pragma unroll
    for (int mi = 0; mi < 4; ++mi)
      af[mi] = *reinterpret_cast<const short8*>(&As[(wr * 64 + mi * 16 + frow) * 32 + fk]);
    #pragma unroll
    for (int ni = 0; ni < 4; ++ni)
      bq[ni] = *reinterpret_cast<const short8*>(&Bs[(wc * 64 + ni * 16 + frow) * 32 + fk]);
    #pragma unroll
    for (int mi = 0; mi < 4; ++mi)
      #pragma unroll
      for (int ni = 0; ni < 4; ++ni)
        acc[mi][ni] = __builtin_amdgcn_mfma_f32_16x16x32_bf16(af[mi], bq[ni], acc[mi][ni], 0, 0, 0);
  }

  const int r0 = bm + wr * 64;
  const int c0 = bn + wc * 64;
  #pragma unroll
  for (int ni = 0; ni < 4; ++ni) {
    const int c = c0 + ni * 16 + (lane & 15);
    const float bv = bias[c];
    #pragma unroll
    for (int mi = 0; mi < 4; ++mi) {
      #pragma unroll
      for (int r = 0; r < 4; ++r) {
        const int row = r0 + mi * 16 + ((lane >> 4) << 2) + r;
        float v = acc[mi][ni][r] + bv;
        if constexpr (RELU) v = fmaxf(v, 0.f);
        if constexpr (OUT_BF16)
          ((unsigned short*)C)[(size_t)row * Nn + c] = f2bf(v);
        else
          ((float*)C)[(size_t)row * Nn + c] = v;
      }
    }
  }
}

// h0 fp32 [N][256] -> bf16 state [N][256]
__global__ void k_h0state(const float* __restrict__ h0, unsigned short* __restrict__ st,
                          long total8) {
  long idx = (long)blockIdx.x * blockDim.x + threadIdx.x;
  if (idx >= total8) return;
  size_t base = (size_t)idx * 8;
  const float4 f0 = *reinterpret_cast<const float4*>(h0 + base);
  const float4 f1 = *reinterpret_cast<const float4*>(h0 + base + 4);
  uint4 o;
  o.x = f2bf(f0.x) | ((unsigned)f2bf(f0.y) << 16);
  o.y = f2bf(f0.z) | ((unsigned)f2bf(f0.w) << 16);
  o.z = f2bf(f1.x) | ((unsigned)f2bf(f1.y) << 16);
  o.w = f2bf(f1.z) | ((unsigned)f2bf(f1.w) << 16);
  *reinterpret_cast<uint4*>(st + base) = o;
}

// ---------------- APPNP propagation step (bf16 state, row-major) ----------------
// 1 wave per node, lane covers 4 dims (u16x4, 8B) -> 256 dims = 512B/row gather.
// 4 nodes / block. fp32 accumulation; h0 teleport term fp32.

template<bool FINAL>
__global__ __launch_bounds__(256)
void k_appnp_b16(const unsigned short* __restrict__ hprev,
                 const float* __restrict__ h0,
                 void* __restrict__ outp,
                 const int* __restrict__ rowptr,
                 const i32x2* __restrict__ edge,
                 const float* __restrict__ dinv, int n) {
  const int lane = threadIdx.x & 63;
  const int i = blockIdx.x * 4 + (threadIdx.x >> 6);
  if (i >= n) return;
  const int beg = rowptr[i];
  const int end = rowptr[i + 1];
  const int d = lane << 2;
  float a0 = 0.f, a1 = 0.f, a2 = 0.f, a3 = 0.f;
  int e = beg;
  for (; e + 4 <= end; e += 4) {
    const i32x2 e0 = __builtin_nontemporal_load(edge + e);
    const i32x2 e1 = __builtin_nontemporal_load(edge + e + 1);
    const i32x2 e2 = __builtin_nontemporal_load(edge + e + 2);
    const i32x2 e3 = __builtin_nontemporal_load(edge + e + 3);
    const float w0 = __int_as_float(e0.y), w1 = __int_as_float(e1.y);
    const float w2 = __int_as_float(e2.y), w3 = __int_as_float(e3.y);
    const u16x4 v0 = *reinterpret_cast<const u16x4*>(hprev + (size_t)e0.x * 256 + d);
    const u16x4 v1 = *reinterpret_cast<const u16x4*>(hprev + (size_t)e1.x * 256 + d);
    const u16x4 v2 = *reinterpret_cast<const u16x4*>(hprev + (size_t)e2.x * 256 + d);
    const u16x4 v3 = *reinterpret_cast<const u16x4*>(hprev + (size_t)e3.x * 256 + d);
    a0 += w0 * bf2f(v0.x) + w1 * bf2f(v1.x) + w2 * bf2f(v2.x) + w3 * bf2f(v3.x);
    a1 += w0 * bf2f(v0.y) + w1 * bf2f(v1.y) + w2 * bf2f(v2.y) + w3 * bf2f(v3.y);
    a2 += w0 * bf2f(v0.z) + w1 * bf2f(v1.z) + w2 * bf2f(v2.z) + w3 * bf2f(v3.z);
    a3 += w0 * bf2f(v0.w) + w1 * bf2f(v1.w) + w2 * bf2f(v2.w) + w3 * bf2f(v3.w);
  }
  for (; e < end; ++e) {
    const i32x2 ee = __builtin_nontemporal_load(edge + e);
    const float w = __int_as_float(ee.y);
    const u16x4 v = *reinterpret_cast<const u16x4*>(hprev + (size_t)ee.x * 256 + d);
    a0 += w * bf2f(v.x); a1 += w * bf2f(v.y); a2 += w * bf2f(v.z); a3 += w * bf2f(v.w);
  }
  const float s = (1.0f - ALPHA_F) * dinv[i];
  const f32x4 h0v = __builtin_nontemporal_load(
      reinterpret_cast<const f32x4*>(h0 + (size_t)i * 256 + d));
  const float o0 = s * a0 + ALPHA_F * h0v.x;
  const float o1 = s * a1 + ALPHA_F * h0v.y;
  const float o2 = s * a2 + ALPHA_F * h0v.z;
  const float o3 = s * a3 + ALPHA_F * h0v.w;
  if constexpr (FINAL) {
    f32x4 o; o.x = o0; o.y = o1; o.z = o2; o.w = o3;
    __builtin_nontemporal_store(o, reinterpret_cast<f32x4*>((float*)outp + (size_t)i * 256 + d));
  } else {
    u16x4 o;
    o.x = f2bf(o0); o.y = f2bf(o1); o.z = f2bf(o2); o.w = f2bf(o3);
    *reinterpret_cast<u16x4*>((unsigned short*)outp + (size_t)i * 256 + d) = o;
  }
}

// ---------------- launch ----------------

extern "C" void kernel_launch(void* const* d_in, const int* in_sizes, int n_in,
                              void* d_out, int out_size, void* d_ws, size_t ws_size,
                              hipStream_t stream) {
  const float* x  = (const float*)d_in[0];
  const int*   ei = (const int*)d_in[1];
  const float* W1 = (const float*)d_in[2];
  const float* b1 = (const float*)d_in[3];
  const float* W2 = (const float*)d_in[4];
  const float* b2 = (const float*)d_in[5];
  const float* W3 = (const float*)d_in[6];
  const float* b3 = (const float*)d_in[7];

  const int HID  = in_sizes[3];            // 512
  const int IN   = in_sizes[2] / HID;      // 512
  const int OUTD = in_sizes[7];            // 256
  const int E    = in_sizes[1] / 2;        // 1,600,000
  const int N    = in_sizes[0] / IN;       // 50,000
  const int Mpad = (N + 127) & ~127;       // 50,048
  const int* src = ei;
  const int* dst = ei + E;

  char* ws = (char*)d_ws;
  size_t off = 0;
  auto alloc = [&](size_t bytes) {
    char* p = ws + off;
    off += (bytes + 255) & ~(size_t)255;
    return p;
  };
  // R1: xb [Mpad][IN] bf16 -> h2 [Mpad][HID] bf16 -> stateB bf16 [N][256]
  char* R1 = alloc((size_t)Mpad * ((IN > HID) ? IN : HID) * 2);
  // R2: h1 [Mpad][HID] bf16 -> stateA bf16 [N][256]
  char* R2 = alloc((size_t)Mpad * HID * 2);
  // R4: h0 fp32 [Mpad][OUTD] (live through all steps)
  char* R4 = alloc((size_t)Mpad * OUTD * 4);
  int*   deg    = (int*)alloc((size_t)N * 4);
  int*   rowptr = (int*)alloc((size_t)(N + 1) * 4);
  int*   cursor = (int*)alloc((size_t)N * 4);
  float* dinv   = (float*)alloc((size_t)N * 4);
  i32x2* edge   = (i32x2*)alloc((size_t)(E + N) * 8);
  unsigned short* W1t = (unsigned short*)alloc((size_t)IN * HID * 2);
  unsigned short* W2t = (unsigned short*)alloc((size_t)HID * HID * 2);
  unsigned short* W3t = (unsigned short*)alloc((size_t)HID * OUTD * 2);
  (void)ws_size; (void)n_in; (void)out_size;

  unsigned short* xb = (unsigned short*)R1;
  unsigned short* h1 = (unsigned short*)R2;
  unsigned short* h2 = (unsigned short*)R1;
  float* h0 = (float*)R4;
  unsigned short* stateA = (unsigned short*)R2;
  unsigned short* stateB = (unsigned short*)R1;

  // graph build
  k_init_deg<<<(N + 255) / 256, 256, 0, stream>>>(deg, N);
  k_hist<<<(E + 255) / 256, 256, 0, stream>>>(dst, deg, E);
  k_scan<<<1, 1024, 0, stream>>>(deg, rowptr, N);
  k_dinv_cursor<<<(N + 255) / 256, 256, 0, stream>>>(deg, rowptr, dinv, cursor, N);
  k_scatter<<<(E + N + 255) / 256, 256, 0, stream>>>(src, dst, cursor, edge, dinv, E, N);

  // converts
  {
    long total8 = (long)Mpad * IN / 8;
    k_f2b8<<<(int)((total8 + 255) / 256), 256, 0, stream>>>(x, xb, N, IN, total8);
    k_wtrans<<<(IN * HID + 255) / 256, 256, 0, stream>>>(W1, W1t, IN, HID);
    k_wtrans<<<(HID * HID + 255) / 256, 256, 0, stream>>>(W2, W2t, HID, HID);
    k_wtrans<<<(HID * OUTD + 255) / 256, 256, 0, stream>>>(W3, W3t, HID, OUTD);
  }

  // MLP encoder (MFMA)
  {
    dim3 blk(256);
    dim3 g1(HID / 128, Mpad / 128);
    k_gemm_mfma<true, true><<<g1, blk, 0, stream>>>(xb, W1t, b1, h1, HID, IN);
    k_gemm_mfma<true, true><<<g1, blk, 0, stream>>>(h1, W2t, b2, h2, HID, HID);
    dim3 g3(OUTD / 128, Mpad / 128);
    k_gemm_mfma<false, false><<<g3, blk, 0, stream>>>(h2, W3t, b3, h0, OUTD, HID);
  }

  // state0 = bf16(h0)  (stateA; h2 in R1 already consumed)
  {
    long total8 = (long)N * OUTD / 8;
    k_h0state<<<(int)((total8 + 255) / 256), 256, 0, stream>>>(h0, stateA, total8);
  }

  // APPNP propagation: ping-pong bf16 states; final (10th) step writes fp32 d_out
  {
    const int nblk = (N + 3) / 4;
    const unsigned short* cur = stateA;
    for (int step = 0; step < K_STEPS - 1; ++step) {
      unsigned short* dbuf = (step % 2 == 0) ? stateB : stateA;
      k_appnp_b16<false><<<nblk, 256, 0, stream>>>(cur, h0, dbuf, rowptr, edge, dinv, N);
      cur = dbuf;
    }
    k_appnp_b16<true><<<nblk, 256, 0, stream>>>(cur, h0, d_out, rowptr, edge, dinv, N);
  }
}

// Round 6
// 1511.497 us; speedup vs baseline: 2.4866x; 1.0995x over previous
//
#include <hip/hip_runtime.h>
#include <hip/hip_bf16.h>
#include <stdint.h>

#define ALPHA_F 0.2f
#define K_STEPS 10

typedef __attribute__((ext_vector_type(8))) short short8;
typedef __attribute__((ext_vector_type(4))) float f32x4;
typedef __attribute__((ext_vector_type(4))) unsigned short u16x4;
typedef __attribute__((ext_vector_type(2))) int i32x2;

__device__ __forceinline__ float bf2f(unsigned short u) {
  union { unsigned int i; float f; } v; v.i = ((unsigned int)u) << 16; return v.f;
}
__device__ __forceinline__ unsigned short f2bf(float f) {
  unsigned int x = __float_as_uint(f);
  unsigned int r = (x + 0x7fffu + ((x >> 16) & 1u)) >> 16;
  return (unsigned short)r;
}

__device__ __forceinline__ void glds16(const void* g, void* l) {
  __builtin_amdgcn_global_load_lds(
      (const __attribute__((address_space(1))) void*)g,
      (__attribute__((address_space(3))) void*)l, 16, 0, 0);
}

// ---------------- graph build ----------------

__global__ void k_hist(const int* __restrict__ dst, int* __restrict__ deg, int E) {
  int e = blockIdx.x * blockDim.x + threadIdx.x;
  if (e < E) atomicAdd(&deg[dst[e]], 1);
}

// multi-block exclusive scan of (deg[i]+1): phase A — per-block scan + block sums
__global__ __launch_bounds__(1024)
void k_scanA(const int* __restrict__ deg, int* __restrict__ rowptr,
             int* __restrict__ bsum, int n) {
  __shared__ int buf[2][1024];
  const int tid = threadIdx.x;
  const int gid = blockIdx.x * 1024 + tid;
  int v = (gid < n) ? (deg[gid] + 1) : 0;  // +1 self-loop
  int sel = 0;
  buf[0][tid] = v;
  __syncthreads();
  #pragma unroll
  for (int off = 1; off < 1024; off <<= 1) {
    int t = buf[sel][tid] + ((tid >= off) ? buf[sel][tid - off] : 0);
    buf[sel ^ 1][tid] = t;
    sel ^= 1;
    __syncthreads();
  }
  if (gid < n) rowptr[gid] = buf[sel][tid] - v;  // exclusive within block
  if (tid == 0) bsum[blockIdx.x] = buf[sel][1023];
}

// phase B — serial exclusive scan of block sums (small)
__global__ void k_scanB(int* __restrict__ bsum, int nb) {
  if (threadIdx.x == 0 && blockIdx.x == 0) {
    int acc = 0;
    for (int i = 0; i < nb; ++i) { int t = bsum[i]; bsum[i] = acc; acc += t; }
    bsum[nb] = acc;
  }
}

// phase C — add block offsets; also writes rowptr[n]
__global__ void k_scanC(int* __restrict__ rowptr, const int* __restrict__ bsum,
                        int n, int nb) {
  int gid = blockIdx.x * blockDim.x + threadIdx.x;
  if (gid < n) rowptr[gid] += bsum[gid >> 10];
  else if (gid == n) rowptr[n] = bsum[nb];
}

__global__ void k_dinv_cursor(const int* __restrict__ deg, const int* __restrict__ rowptr,
                              float* __restrict__ dinv, int* __restrict__ cursor, int n) {
  int i = blockIdx.x * blockDim.x + threadIdx.x;
  if (i < n) {
    dinv[i] = 1.0f / sqrtf((float)(deg[i] + 1));
    cursor[i] = rowptr[i];
  }
}

// edge[pos] = {src, bits(dinv[src])}
__global__ void k_scatter(const int* __restrict__ src, const int* __restrict__ dst,
                          int* __restrict__ cursor, i32x2* __restrict__ edge,
                          const float* __restrict__ dinv, int E, int n) {
  int idx = blockIdx.x * blockDim.x + threadIdx.x;
  if (idx >= E + n) return;
  int s, d;
  if (idx < E) { s = src[idx]; d = dst[idx]; }
  else         { s = d = idx - E; }
  int pos = atomicAdd(&cursor[d], 1);
  i32x2 e;
  e.x = s;
  e.y = __float_as_int(dinv[s]);
  edge[pos] = e;
}

// ---------------- converts ----------------

// fp32 -> bf16, 8 elems/thread, zero-fill pad rows
__global__ void k_f2b8(const float* __restrict__ src, unsigned short* __restrict__ dst,
                       int validRows, int cols, long total8) {
  long idx = (long)blockIdx.x * blockDim.x + threadIdx.x;
  if (idx >= total8) return;
  size_t base = (size_t)idx * 8;
  int row = (int)(base / (size_t)cols);
  uint4 o;
  if (row < validRows) {
    const float4 f0 = *reinterpret_cast<const float4*>(src + base);
    const float4 f1 = *reinterpret_cast<const float4*>(src + base + 4);
    o.x = f2bf(f0.x) | ((unsigned)f2bf(f0.y) << 16);
    o.y = f2bf(f0.z) | ((unsigned)f2bf(f0.w) << 16);
    o.z = f2bf(f1.x) | ((unsigned)f2bf(f1.y) << 16);
    o.w = f2bf(f1.z) | ((unsigned)f2bf(f1.w) << 16);
  } else {
    o = make_uint4(0, 0, 0, 0);
  }
  *reinterpret_cast<uint4*>(dst + base) = o;
}

// W [K][Nw] fp32 -> Wt [Nw][K] bf16, LDS-tiled 32x32 (coalesced both sides)
__global__ __launch_bounds__(256)
void k_wtrans(const float* __restrict__ W, unsigned short* __restrict__ Wt,
              int K, int Nw) {
  __shared__ float tile[32][33];
  const int bn = blockIdx.x * 32;  // Nw dir
  const int bk = blockIdx.y * 32;  // K dir
  const int tx = threadIdx.x & 31;
  const int ty = threadIdx.x >> 5;  // 0..7
  #pragma unroll
  for (int r = 0; r < 32; r += 8)
    tile[r + ty][tx] = W[(size_t)(bk + r + ty) * Nw + bn + tx];
  __syncthreads();
  #pragma unroll
  for (int r = 0; r < 32; r += 8)
    Wt[(size_t)(bn + r + ty) * K + bk + tx] = f2bf(tile[tx][r + ty]);
}

// ---------------- MFMA GEMM ----------------
// C[M][Nn] = A[M][K]_bf16 @ Bt[Nn][K]_bf16^T + bias, 128x128 tile, BK=32,
// 256 threads = 4 waves (2x2), each wave 64x64 = 4x4 fragments of 16x16x32.

template<bool OUT_BF16, bool RELU>
__global__ __launch_bounds__(256)
void k_gemm_mfma(const unsigned short* __restrict__ A,
                 const unsigned short* __restrict__ Bt,
                 const float* __restrict__ bias,
                 void* __restrict__ C, int Nn, int K) {
  __shared__ unsigned short As[128 * 32];
  __shared__ unsigned short Bs[128 * 32];
  const int tid = threadIdx.x;
  const int lane = tid & 63;
  const int wid = tid >> 6;
  const int wr = wid >> 1, wc = wid & 1;
  const int bm = blockIdx.y * 128;
  const int bn = blockIdx.x * 128;

  f32x4 acc[4][4];
  #pragma unroll
  for (int i = 0; i < 4; ++i)
    #pragma unroll
    for (int j = 0; j < 4; ++j) acc[i][j] = (f32x4)0.f;

  const int srow = tid >> 2;
  const int skg = (tid & 3) << 3;
  const unsigned short* Ag = A + (size_t)(bm + srow) * K + skg;
  const unsigned short* Bg = Bt + (size_t)(bn + srow) * K + skg;
  unsigned short* lA = As + (wid << 9);
  unsigned short* lB = Bs + (wid << 9);

  const int frow = lane & 15;
  const int fk = (lane >> 4) << 3;

  for (int k0 = 0; k0 < K; k0 += 32) {
    __syncthreads();
    glds16(Ag + k0, lA);
    glds16(Ag + (size_t)64 * K + k0, lA + 2048);
    glds16(Bg + k0, lB);
    glds16(Bg + (size_t)64 * K + k0, lB + 2048);
    __syncthreads();

    short8 af[4], bq[4];
    #pragma unroll
    for (int mi = 0; mi < 4; ++mi)
      af[mi] = *reinterpret_cast<const short8*>(&As[(wr * 64 + mi * 16 + frow) * 32 + fk]);
    #pragma unroll
    for (int ni = 0; ni < 4; ++ni)
      bq[ni] = *reinterpret_cast<const short8*>(&Bs[(wc * 64 + ni * 16 + frow) * 32 + fk]);
    #pragma unroll
    for (int mi = 0; mi < 4; ++mi)
      #pragma unroll
      for (int ni = 0; ni < 4; ++ni)
        acc[mi][ni] = __builtin_amdgcn_mfma_f32_16x16x32_bf16(af[mi], bq[ni], acc[mi][ni], 0, 0, 0);
  }

  const int r0 = bm + wr * 64;
  const int c0 = bn + wc * 64;
  #pragma unroll
  for (int ni = 0; ni < 4; ++ni) {
    const int c = c0 + ni * 16 + (lane & 15);
    const float bv = bias[c];
    #pragma unroll
    for (int mi = 0; mi < 4; ++mi) {
      #pragma unroll
      for (int r = 0; r < 4; ++r) {
        const int row = r0 + mi * 16 + ((lane >> 4) << 2) + r;
        float v = acc[mi][ni][r] + bv;
        if constexpr (RELU) v = fmaxf(v, 0.f);
        if constexpr (OUT_BF16)
          ((unsigned short*)C)[(size_t)row * Nn + c] = f2bf(v);
        else
          ((float*)C)[(size_t)row * Nn + c] = v;
      }
    }
  }
}

// ---------------- APPNP propagation step ----------------
// bf16 state [N][256], 1 wave per node, lane = 4 dims (u16x4). Inner loop is
// 2-stage software-pipelined: edges prefetched 2 quads ahead, gathers issued
// 1 quad ahead, so only the accumulate waits on memory.

#define NTLD(p) __builtin_nontemporal_load(p)

template<bool FINAL>
__global__ __launch_bounds__(256)
void k_appnp_b16(const unsigned short* __restrict__ hprev,
                 const unsigned short* __restrict__ h0b,
                 void* __restrict__ outp,
                 const int* __restrict__ rowptr,
                 const i32x2* __restrict__ edge,
                 const float* __restrict__ dinv, int n) {
  const int lane = threadIdx.x & 63;
  const int i = blockIdx.x * 4 + (threadIdx.x >> 6);
  if (i >= n) return;
  const int beg = rowptr[i];
  const int end = rowptr[i + 1];
  const int d = lane << 2;
  float a0 = 0.f, a1 = 0.f, a2 = 0.f, a3 = 0.f;

  auto gat = [&](int j) -> u16x4 {
    return *reinterpret_cast<const u16x4*>(hprev + (size_t)j * 256 + d);
  };
  auto accq = [&](float w, u16x4 v) {
    a0 += w * bf2f(v.x); a1 += w * bf2f(v.y);
    a2 += w * bf2f(v.z); a3 += w * bf2f(v.w);
  };

  const int quads = (end - beg) >> 2;
  int e = beg;
  if (quads >= 2) {
    // prologue: edges for quad0 (consumed into gathers V), edges for quad1 (B)
    i32x2 t0 = NTLD(edge + e),     t1 = NTLD(edge + e + 1);
    i32x2 t2 = NTLD(edge + e + 2), t3 = NTLD(edge + e + 3);
    i32x2 B0 = NTLD(edge + e + 4), B1 = NTLD(edge + e + 5);
    i32x2 B2 = NTLD(edge + e + 6), B3 = NTLD(edge + e + 7);
    u16x4 V0 = gat(t0.x), V1 = gat(t1.x), V2 = gat(t2.x), V3 = gat(t3.x);
    float w0 = __int_as_float(t0.y), w1 = __int_as_float(t1.y);
    float w2 = __int_as_float(t2.y), w3 = __int_as_float(t3.y);
    for (int q = 2; q < quads; ++q) {
      const i32x2* ep = edge + e + (q << 2);
      const i32x2 C0 = NTLD(ep),     C1 = NTLD(ep + 1);
      const i32x2 C2 = NTLD(ep + 2), C3 = NTLD(ep + 3);
      const u16x4 U0 = gat(B0.x), U1 = gat(B1.x), U2 = gat(B2.x), U3 = gat(B3.x);
      const float x0 = __int_as_float(B0.y), x1 = __int_as_float(B1.y);
      const float x2 = __int_as_float(B2.y), x3 = __int_as_float(B3.y);
      accq(w0, V0); accq(w1, V1); accq(w2, V2); accq(w3, V3);
      V0 = U0; V1 = U1; V2 = U2; V3 = U3;
      w0 = x0; w1 = x1; w2 = x2; w3 = x3;
      B0 = C0; B1 = C1; B2 = C2; B3 = C3;
    }
    // epilogue: gather last quad (B), accumulate both pending quads
    const u16x4 U0 = gat(B0.x), U1 = gat(B1.x), U2 = gat(B2.x), U3 = gat(B3.x);
    accq(w0, V0); accq(w1, V1); accq(w2, V2); accq(w3, V3);
    accq(__int_as_float(B0.y), U0); accq(__int_as_float(B1.y), U1);
    accq(__int_as_float(B2.y), U2); accq(__int_as_float(B3.y), U3);
    e += quads << 2;
  } else if (quads == 1) {
    const i32x2 t0 = NTLD(edge + e),     t1 = NTLD(edge + e + 1);
    const i32x2 t2 = NTLD(edge + e + 2), t3 = NTLD(edge + e + 3);
    const u16x4 V0 = gat(t0.x), V1 = gat(t1.x), V2 = gat(t2.x), V3 = gat(t3.x);
    accq(__int_as_float(t0.y), V0); accq(__int_as_float(t1.y), V1);
    accq(__int_as_float(t2.y), V2); accq(__int_as_float(t3.y), V3);
    e += 4;
  }
  for (; e < end; ++e) {
    const i32x2 ee = NTLD(edge + e);
    accq(__int_as_float(ee.y), gat(ee.x));
  }

  const float s = (1.0f - ALPHA_F) * dinv[i];
  const u16x4 hv = NTLD(reinterpret_cast<const u16x4*>(h0b + (size_t)i * 256 + d));
  const float o0 = s * a0 + ALPHA_F * bf2f(hv.x);
  const float o1 = s * a1 + ALPHA_F * bf2f(hv.y);
  const float o2 = s * a2 + ALPHA_F * bf2f(hv.z);
  const float o3 = s * a3 + ALPHA_F * bf2f(hv.w);
  if constexpr (FINAL) {
    f32x4 o; o.x = o0; o.y = o1; o.z = o2; o.w = o3;
    __builtin_nontemporal_store(o, reinterpret_cast<f32x4*>((float*)outp + (size_t)i * 256 + d));
  } else {
    u16x4 o;
    o.x = f2bf(o0); o.y = f2bf(o1); o.z = f2bf(o2); o.w = f2bf(o3);
    *reinterpret_cast<u16x4*>((unsigned short*)outp + (size_t)i * 256 + d) = o;
  }
}

// ---------------- launch ----------------

extern "C" void kernel_launch(void* const* d_in, const int* in_sizes, int n_in,
                              void* d_out, int out_size, void* d_ws, size_t ws_size,
                              hipStream_t stream) {
  const float* x  = (const float*)d_in[0];
  const int*   ei = (const int*)d_in[1];
  const float* W1 = (const float*)d_in[2];
  const float* b1 = (const float*)d_in[3];
  const float* W2 = (const float*)d_in[4];
  const float* b2 = (const float*)d_in[5];
  const float* W3 = (const float*)d_in[6];
  const float* b3 = (const float*)d_in[7];

  const int HID  = in_sizes[3];            // 512
  const int IN   = in_sizes[2] / HID;      // 512
  const int OUTD = in_sizes[7];            // 256
  const int E    = in_sizes[1] / 2;        // 1,600,000
  const int N    = in_sizes[0] / IN;       // 50,000
  const int Mpad = (N + 127) & ~127;       // 50,048
  const int* src = ei;
  const int* dst = ei + E;

  char* ws = (char*)d_ws;
  size_t off = 0;
  auto alloc = [&](size_t bytes) {
    char* p = ws + off;
    off += (bytes + 255) & ~(size_t)255;
    return p;
  };
  // R1: xb [Mpad][IN] bf16 -> h2 [Mpad][HID] bf16 -> stateB bf16 [N][256]
  char* R1 = alloc((size_t)Mpad * ((IN > HID) ? IN : HID) * 2);
  // R2: h1 [Mpad][HID] bf16 -> stateA bf16 [N][256]
  char* R2 = alloc((size_t)Mpad * HID * 2);
  // R4: h0b bf16 [Mpad][OUTD] (persistent teleport term)
  char* R4 = alloc((size_t)Mpad * OUTD * 2);
  int*   deg    = (int*)alloc((size_t)N * 4);
  int*   rowptr = (int*)alloc((size_t)(N + 1) * 4);
  int*   cursor = (int*)alloc((size_t)N * 4);
  float* dinv   = (float*)alloc((size_t)N * 4);
  int*   bsum   = (int*)alloc((size_t)256 * 4);
  i32x2* edge   = (i32x2*)alloc((size_t)(E + N + 8) * 8);  // +8: prefetch pad
  unsigned short* W1t = (unsigned short*)alloc((size_t)IN * HID * 2);
  unsigned short* W2t = (unsigned short*)alloc((size_t)HID * HID * 2);
  unsigned short* W3t = (unsigned short*)alloc((size_t)HID * OUTD * 2);
  (void)ws_size; (void)n_in; (void)out_size;

  unsigned short* xb = (unsigned short*)R1;
  unsigned short* h1 = (unsigned short*)R2;
  unsigned short* h2 = (unsigned short*)R1;
  unsigned short* h0b = (unsigned short*)R4;
  unsigned short* stateA = (unsigned short*)R2;
  unsigned short* stateB = (unsigned short*)R1;

  // graph build
  hipMemsetAsync(deg, 0, (size_t)N * 4, stream);
  k_hist<<<(E + 255) / 256, 256, 0, stream>>>(dst, deg, E);
  const int nb = (N + 1023) / 1024;
  k_scanA<<<nb, 1024, 0, stream>>>(deg, rowptr, bsum, N);
  k_scanB<<<1, 64, 0, stream>>>(bsum, nb);
  k_scanC<<<(N + 256) / 256, 256, 0, stream>>>(rowptr, bsum, N, nb);
  k_dinv_cursor<<<(N + 255) / 256, 256, 0, stream>>>(deg, rowptr, dinv, cursor, N);
  k_scatter<<<(E + N + 255) / 256, 256, 0, stream>>>(src, dst, cursor, edge, dinv, E, N);

  // converts
  {
    long total8 = (long)Mpad * IN / 8;
    k_f2b8<<<(int)((total8 + 255) / 256), 256, 0, stream>>>(x, xb, N, IN, total8);
    dim3 tb(256);
    k_wtrans<<<dim3(HID / 32, IN / 32), tb, 0, stream>>>(W1, W1t, IN, HID);
    k_wtrans<<<dim3(HID / 32, HID / 32), tb, 0, stream>>>(W2, W2t, HID, HID);
    k_wtrans<<<dim3(OUTD / 32, HID / 32), tb, 0, stream>>>(W3, W3t, HID, OUTD);
  }

  // MLP encoder (MFMA); GEMM3 emits bf16 h0b directly
  {
    dim3 blk(256);
    dim3 g1(HID / 128, Mpad / 128);
    k_gemm_mfma<true, true><<<g1, blk, 0, stream>>>(xb, W1t, b1, h1, HID, IN);
    k_gemm_mfma<true, true><<<g1, blk, 0, stream>>>(h1, W2t, b2, h2, HID, HID);
    dim3 g3(OUTD / 128, Mpad / 128);
    k_gemm_mfma<true, false><<<g3, blk, 0, stream>>>(h2, W3t, b3, h0b, OUTD, HID);
  }

  // APPNP propagation: step0 reads h0b; steps ping-pong stateA/B; final -> d_out
  {
    const int nblk = (N + 3) / 4;
    const unsigned short* cur = h0b;
    for (int step = 0; step < K_STEPS - 1; ++step) {
      unsigned short* dbuf = (step % 2 == 0) ? stateA : stateB;
      k_appnp_b16<false><<<nblk, 256, 0, stream>>>(cur, h0b, dbuf, rowptr, edge, dinv, N);
      cur = dbuf;
    }
    k_appnp_b16<true><<<nblk, 256, 0, stream>>>(cur, h0b, d_out, rowptr, edge, dinv, N);
  }
}